// Round 1
// baseline (411.795 us; speedup 1.0000x reference)
//
#include <hip/hip_runtime.h>
#include <math.h>

#define BATCH   131072
#define IN_DIMS 512
#define TPB     256
#define CHUNK   32
#define NCHUNK  (IN_DIMS / CHUNK)   // 16
#define LSTRIDE 33                  // +1 pad: LDS read bank = (t+k)%32, conflict-free

// Per-block: stage x[256 rows x 32 cols] in LDS (coalesced), each thread owns one
// row and accumulates its 9-dim projection against scalar-loaded W; then each
// thread does a fp64 Jacobi eigensolve of M^T M and emits the nearest rotation.
__global__ __launch_bounds__(TPB, 2)
void svdo_rot_kernel(const float* __restrict__ x,
                     const float* __restrict__ W,
                     const float* __restrict__ bias,
                     float* __restrict__ out)
{
    __shared__ float tile[TPB * LSTRIDE];   // 33792 B

    const int t = threadIdx.x;
    const int row0 = blockIdx.x * TPB;
    const float* xb = x + (size_t)row0 * IN_DIMS;

    float acc[9];
#pragma unroll
    for (int j = 0; j < 9; ++j) acc[j] = bias[j];

    // ---- phase 1: tiled GEMV, software-pipelined (prefetch chunk c+1 into regs) ----
    float4 pre[8];
#pragma unroll
    for (int i = 0; i < 8; ++i) {
        int f = i * TPB + t;
        int r = f >> 3, q = f & 7;
        pre[i] = *reinterpret_cast<const float4*>(xb + r * IN_DIMS + q * 4);
    }

#pragma unroll 1
    for (int c = 0; c < NCHUNK; ++c) {
        __syncthreads();
#pragma unroll
        for (int i = 0; i < 8; ++i) {
            int f = i * TPB + t;
            int r = f >> 3, q = f & 7;
            float* p = &tile[r * LSTRIDE + q * 4];
            p[0] = pre[i].x; p[1] = pre[i].y; p[2] = pre[i].z; p[3] = pre[i].w;
        }
        __syncthreads();
        if (c + 1 < NCHUNK) {
#pragma unroll
            for (int i = 0; i < 8; ++i) {
                int f = i * TPB + t;
                int r = f >> 3, q = f & 7;
                pre[i] = *reinterpret_cast<const float4*>(
                    xb + r * IN_DIMS + (c + 1) * CHUNK + q * 4);
            }
        }
        float xv[CHUNK];
#pragma unroll
        for (int k = 0; k < CHUNK; ++k) xv[k] = tile[t * LSTRIDE + k];
        const float* wc = W + c * CHUNK;
#pragma unroll
        for (int j = 0; j < 9; ++j) {
            float s = acc[j];
            const float* wr = wc + j * IN_DIMS;   // uniform address -> s_load
#pragma unroll
            for (int k = 0; k < CHUNK; ++k) s = fmaf(xv[k], wr[k], s);
            acc[j] = s;
        }
    }

    // ---- phase 2: nearest rotation of the 3x3 M (row-major acc[3r+c]), fp64 ----
    double m0 = acc[0], m1 = acc[1], m2 = acc[2];
    double m3 = acc[3], m4 = acc[4], m5 = acc[5];
    double m6 = acc[6], m7 = acc[7], m8 = acc[8];

    // A = M^T M (symmetric)
    double A00 = m0*m0 + m3*m3 + m6*m6;
    double A01 = m0*m1 + m3*m4 + m6*m7;
    double A02 = m0*m2 + m3*m5 + m6*m8;
    double A11 = m1*m1 + m4*m4 + m7*m7;
    double A12 = m1*m2 + m4*m5 + m7*m8;
    double A22 = m2*m2 + m5*m5 + m8*m8;

    // V = I (columns V0,V1,V2 are eigenvectors)
    double V0x = 1, V0y = 0, V0z = 0;
    double V1x = 0, V1y = 1, V1z = 0;
    double V2x = 0, V2y = 0, V2z = 1;

#define JACOBI_ROT(App, Aqq, Apq, Arp, Arq, Px, Py, Pz, Qx, Qy, Qz)            \
    do { if (fabs(Apq) > 1e-300) {                                             \
        double tau = (Aqq - App) / (2.0 * Apq);                                \
        double tt  = copysign(1.0, tau) / (fabs(tau) + sqrt(1.0 + tau*tau));   \
        double cc  = 1.0 / sqrt(1.0 + tt*tt);                                  \
        double ss  = tt * cc;                                                  \
        App -= tt * Apq; Aqq += tt * Apq;                                      \
        double nrp = cc*Arp - ss*Arq;  Arq = ss*Arp + cc*Arq;  Arp = nrp;      \
        Apq = 0.0;                                                             \
        double tx = cc*Px - ss*Qx;  Qx = ss*Px + cc*Qx;  Px = tx;              \
        double ty = cc*Py - ss*Qy;  Qy = ss*Py + cc*Qy;  Py = ty;              \
        double tz = cc*Pz - ss*Qz;  Qz = ss*Pz + cc*Qz;  Pz = tz;              \
    } } while (0)

#pragma unroll 1
    for (int sweep = 0; sweep < 6; ++sweep) {
        JACOBI_ROT(A00, A11, A01, A02, A12, V0x,V0y,V0z, V1x,V1y,V1z);
        JACOBI_ROT(A00, A22, A02, A01, A12, V0x,V0y,V0z, V2x,V2y,V2z);
        JACOBI_ROT(A11, A22, A12, A01, A02, V1x,V1y,V1z, V2x,V2y,V2z);
    }

    // sort eigenpairs descending (column swaps, no dynamic indexing)
#define CSWAP(La, Lb, Ax, Ay, Az, Bx, By, Bz)                                  \
    do { if (La < Lb) { double _t_;                                            \
        _t_ = La; La = Lb; Lb = _t_;                                           \
        _t_ = Ax; Ax = Bx; Bx = _t_;                                           \
        _t_ = Ay; Ay = By; By = _t_;                                           \
        _t_ = Az; Az = Bz; Bz = _t_;                                           \
    } } while (0)

    CSWAP(A00, A11, V0x,V0y,V0z, V1x,V1y,V1z);
    CSWAP(A00, A22, V0x,V0y,V0z, V2x,V2y,V2z);
    CSWAP(A11, A22, V1x,V1y,V1z, V2x,V2y,V2z);

    // u1 = normalize(M v1)
    double b1x = m0*V0x + m1*V0y + m2*V0z;
    double b1y = m3*V0x + m4*V0y + m5*V0z;
    double b1z = m6*V0x + m7*V0y + m8*V0z;
    double inv1 = 1.0 / sqrt(b1x*b1x + b1y*b1y + b1z*b1z + 1e-300);
    double u1x = b1x*inv1, u1y = b1y*inv1, u1z = b1z*inv1;

    // u2 = normalize(M v2 - (u1 . M v2) u1)
    double b2x = m0*V1x + m1*V1y + m2*V1z;
    double b2y = m3*V1x + m4*V1y + m5*V1z;
    double b2z = m6*V1x + m7*V1y + m8*V1z;
    double d12 = u1x*b2x + u1y*b2y + u1z*b2z;
    b2x -= d12*u1x; b2y -= d12*u1y; b2z -= d12*u1z;
    double inv2 = 1.0 / sqrt(b2x*b2x + b2y*b2y + b2z*b2z + 1e-300);
    double u2x = b2x*inv2, u2y = b2y*inv2, u2z = b2z*inv2;

    // u3 = u1 x u2  (det(U) = +1 by construction)
    double u3x = u1y*u2z - u1z*u2y;
    double u3y = u1z*u2x - u1x*u2z;
    double u3z = u1x*u2y - u1y*u2x;

    // e = sign(det V); R = u1 v1^T + u2 v2^T + e u3 v3^T
    double cxx = V1y*V2z - V1z*V2y;
    double cyy = V1z*V2x - V1x*V2z;
    double czz = V1x*V2y - V1y*V2x;
    double detV = V0x*cxx + V0y*cyy + V0z*czz;
    double e = (detV >= 0.0) ? 1.0 : -1.0;
    double w3x = e*u3x, w3y = e*u3y, w3z = e*u3z;

    float* o = out + (size_t)(row0 + t) * 9;
    o[0] = (float)(u1x*V0x + u2x*V1x + w3x*V2x);
    o[1] = (float)(u1x*V0y + u2x*V1y + w3x*V2y);
    o[2] = (float)(u1x*V0z + u2x*V1z + w3x*V2z);
    o[3] = (float)(u1y*V0x + u2y*V1x + w3y*V2x);
    o[4] = (float)(u1y*V0y + u2y*V1y + w3y*V2y);
    o[5] = (float)(u1y*V0z + u2y*V1z + w3y*V2z);
    o[6] = (float)(u1z*V0x + u2z*V1x + w3z*V2x);
    o[7] = (float)(u1z*V0y + u2z*V1y + w3z*V2y);
    o[8] = (float)(u1z*V0z + u2z*V1z + w3z*V2z);
}

extern "C" void kernel_launch(void* const* d_in, const int* in_sizes, int n_in,
                              void* d_out, int out_size, void* d_ws, size_t ws_size,
                              hipStream_t stream) {
    const float* x  = (const float*)d_in[0];
    const float* W  = (const float*)d_in[1];
    const float* b  = (const float*)d_in[2];
    float* out = (float*)d_out;
    svdo_rot_kernel<<<dim3(BATCH / TPB), dim3(TPB), 0, stream>>>(x, W, b, out);
}